// Round 7
// baseline (277.261 us; speedup 1.0000x reference)
//
#include <hip/hip_runtime.h>
#include <cstdint>
#include <cstddef>

#define NEGV  -1.0e9f
// 0.125 * log2(e): attention computed in exp2 units
#define QSCALE 0.18033688011112042f

typedef _Float16 h8 __attribute__((ext_vector_type(8)));
typedef _Float16 h4 __attribute__((ext_vector_type(4)));
typedef float    f4 __attribute__((ext_vector_type(4)));

// ---------------------------------------------------------------------------
// ws layout (f16 elements):
//  Wqt: [3][1536][512]  (W^T)   2359296
//  Wot: [3][512][512]   (W^T)    786432
//  Qh : [3][8][8][512][64] (q*QSCALE)  6291456
//  Kh : [8][8][1536][64]        6291456
//  Vt : [8][8][64][1536] (V^T)  6291456
//  Oh : [3][4096][512]          6291456
// ---------------------------------------------------------------------------

static __device__ inline h8 cvt8(float4 a, float4 b) {
    h8 r = { (_Float16)a.x, (_Float16)a.y, (_Float16)a.z, (_Float16)a.w,
             (_Float16)b.x, (_Float16)b.y, (_Float16)b.z, (_Float16)b.w };
    return r;
}

// ========== merged W transpose+cvt: Wqkv (512x1536) and Wout (512x512) ==========
__global__ __launch_bounds__(256) void wt_cvt(
    const float* __restrict__ q0, const float* __restrict__ q1, const float* __restrict__ q2,
    const float* __restrict__ o0, const float* __restrict__ o1, const float* __restrict__ o2,
    _Float16* __restrict__ Wqt, _Float16* __restrict__ Wot)
{
    const int mod = blockIdx.z;
    const int flat = blockIdx.x;
    const float* s;
    _Float16* d;
    int C, bx, by;
    if (flat < 768) {
        C = 1536; bx = flat % 48; by = flat / 48;
        s = (mod == 0) ? q0 : ((mod == 1) ? q1 : q2);
        d = Wqt + (size_t)mod * 1536 * 512;
    } else {
        C = 512; bx = (flat - 768) % 16; by = (flat - 768) / 16;
        s = (mod == 0) ? o0 : ((mod == 1) ? o1 : o2);
        d = Wot + (size_t)mod * 512 * 512;
    }
    const int c0 = bx * 32, r0 = by * 32;
    __shared__ float tile[32][33];
    const int tr = threadIdx.x >> 3;
    const int tc = (threadIdx.x & 7) * 4;
    float4 v = *reinterpret_cast<const float4*>(&s[(size_t)(r0 + tr) * C + c0 + tc]);
    tile[tr][tc + 0] = v.x; tile[tr][tc + 1] = v.y; tile[tr][tc + 2] = v.z; tile[tr][tc + 3] = v.w;
    __syncthreads();
    h4 o = { (_Float16)tile[tc + 0][tr], (_Float16)tile[tc + 1][tr],
             (_Float16)tile[tc + 2][tr], (_Float16)tile[tc + 3][tr] };
    *reinterpret_cast<h4*>(&d[(size_t)(c0 + tr) * 512 + r0 + tc]) = o;
}

// ======================= QKV projection (f16 MFMA, BK=64) =======================
__global__ __launch_bounds__(256) void qkv_gemm_f16(
    const float* __restrict__ x0, const float* __restrict__ x1, const float* __restrict__ x2,
    const _Float16* __restrict__ Wqt,
    _Float16* __restrict__ Qh, _Float16* __restrict__ Kh, _Float16* __restrict__ Vt)
{
    const int mod = blockIdx.z;
    const float* __restrict__ A = (mod == 0) ? x0 : ((mod == 1) ? x1 : x2);
    const _Float16* __restrict__ Bw = Wqt + (size_t)mod * 1536 * 512;

    __shared__ _Float16 smem[2 * 128 * 72];   // 36864 B
    _Float16* As = smem;                 // [m][k] stride 72
    _Float16* Bs = smem + 128 * 72;      // [n][k]

    const int t = threadIdx.x;
    const int brow = blockIdx.x * 128, bcol = blockIdx.y * 128;
    const int w = t >> 6, l = t & 63;
    const int wr = (w >> 1) * 64, wc = (w & 1) * 64;
    const int lr = l & 15, lg = l >> 4, lk = lg * 8;

    const int sm = t >> 1, sk = (t & 1) * 32;
    const float*    __restrict__ aRow = &A [(size_t)(brow + sm) * 512 + sk];
    const _Float16* __restrict__ bRow = &Bw[(size_t)(bcol + sm) * 512 + sk];
    _Float16* aDst = &As[sm * 72 + sk];
    _Float16* bDst = &Bs[sm * 72 + sk];

    f4 acc[4][4] = {};
    float4 ax[8];
    h8 bx[4];

#pragma unroll
    for (int j = 0; j < 8; j++) ax[j] = *reinterpret_cast<const float4*>(&aRow[j * 4]);
#pragma unroll
    for (int j = 0; j < 4; j++) bx[j] = *reinterpret_cast<const h8*>(&bRow[j * 8]);
#pragma unroll
    for (int j = 0; j < 4; j++) {
        *reinterpret_cast<h8*>(&aDst[j * 8]) = cvt8(ax[2 * j], ax[2 * j + 1]);
        *reinterpret_cast<h8*>(&bDst[j * 8]) = bx[j];
    }

    for (int k0 = 0; k0 < 512; k0 += 64) {
        __syncthreads();
        const bool more = (k0 + 64) < 512;
        if (more) {
            const int kn = k0 + 64;
#pragma unroll
            for (int j = 0; j < 8; j++) ax[j] = *reinterpret_cast<const float4*>(&aRow[kn + j * 4]);
#pragma unroll
            for (int j = 0; j < 4; j++) bx[j] = *reinterpret_cast<const h8*>(&bRow[kn + j * 8]);
        }
#pragma unroll
        for (int ks = 0; ks < 64; ks += 32) {
            h8 af[4], bf[4];
#pragma unroll
            for (int m = 0; m < 4; m++)
                af[m] = *reinterpret_cast<h8*>(&As[(wr + m * 16 + lr) * 72 + ks + lk]);
#pragma unroll
            for (int n = 0; n < 4; n++)
                bf[n] = *reinterpret_cast<h8*>(&Bs[(wc + n * 16 + lr) * 72 + ks + lk]);
            __builtin_amdgcn_s_setprio(1);
#pragma unroll
            for (int m = 0; m < 4; m++)
#pragma unroll
                for (int n = 0; n < 4; n++)
                    acc[m][n] = __builtin_amdgcn_mfma_f32_16x16x32_f16(af[m], bf[n], acc[m][n], 0, 0, 0);
            __builtin_amdgcn_s_setprio(0);
        }
        __syncthreads();
        if (more) {
#pragma unroll
            for (int j = 0; j < 4; j++) {
                *reinterpret_cast<h8*>(&aDst[j * 8]) = cvt8(ax[2 * j], ax[2 * j + 1]);
                *reinterpret_cast<h8*>(&bDst[j * 8]) = bx[j];
            }
        }
    }

    const int sec = bcol >> 9;                    // 0=q 1=k 2=v
    const int b = brow >> 9;
    const int nbase = brow & 511;
    const int cbase = bcol - (sec << 9);

    if (sec == 2) {
#pragma unroll
        for (int m = 0; m < 4; m++) {
            const int n = nbase + wr + m * 16 + lg * 4;
#pragma unroll
            for (int nn = 0; nn < 4; nn++) {
                const int cis = cbase + wc + nn * 16 + lr;
                const int hh = cis >> 6, d = cis & 63;
                h4 pv = { (_Float16)acc[m][nn][0], (_Float16)acc[m][nn][1],
                          (_Float16)acc[m][nn][2], (_Float16)acc[m][nn][3] };
                *reinterpret_cast<h4*>(&Vt[(((size_t)b * 8 + hh) * 64 + d) * 1536 + mod * 512 + n]) = pv;
            }
        }
    } else {
        const float scl = (sec == 0) ? QSCALE : 1.0f;
        _Float16 (*Ts)[136] = reinterpret_cast<_Float16(*)[136]>(smem);
#pragma unroll
        for (int pass = 0; pass < 2; pass++) {
            __syncthreads();
            if ((w >> 1) == pass) {
#pragma unroll
                for (int m = 0; m < 4; m++)
#pragma unroll
                    for (int nn = 0; nn < 4; nn++)
#pragma unroll
                        for (int reg = 0; reg < 4; reg++)
                            Ts[m * 16 + lg * 4 + reg][wc + nn * 16 + lr] =
                                (_Float16)(acc[m][nn][reg] * scl);
            }
            __syncthreads();
#pragma unroll
            for (int it = 0; it < 4; it++) {
                const int idx = t + it * 256;
                const int r = idx >> 4, c = (idx & 15) * 8;
                h8 v = *reinterpret_cast<h8*>(&Ts[r][c]);
                const int n = nbase + pass * 64 + r;
                const int cis = cbase + c;
                const int hh = cis >> 6, d = cis & 63;
                if (sec == 0)
                    *reinterpret_cast<h8*>(&Qh[((((size_t)mod * 8 + b) * 8 + hh) * 512 + n) * 64 + d]) = v;
                else
                    *reinterpret_cast<h8*>(&Kh[(((size_t)b * 8 + hh) * 1536 + mod * 512 + n) * 64 + d]) = v;
            }
        }
    }
}

// ======================= attention (KVBLK=128: half the barriers) =======================
// block: 512 thr = 8 waves; QBLK=128 (wave w owns 16 q rows). grid (bh, qtile, mod).
__global__ __launch_bounds__(512) void attn_f16(
    const _Float16* __restrict__ Qh, const _Float16* __restrict__ Kh, const _Float16* __restrict__ Vt,
    const int* __restrict__ m0, const int* __restrict__ m1, const int* __restrict__ m2,
    _Float16* __restrict__ Oh)
{
    const int mod = blockIdx.z;
    const int bh = blockIdx.x, b = bh >> 3, h = bh & 7;
    const int q0 = blockIdx.y * 128;

    __shared__ _Float16 Ks[128 * 72];    // [key][d]
    __shared__ _Float16 Vs[64 * 136];    // [d][key]
    __shared__ _Float16 Ps[128 * 136];   // [q][key] (wave-local rows)

    const int t = threadIdx.x, w = t >> 6, l = t & 63;
    const int lr = l & 15, lg = l >> 4, lk = lg * 8;

    const _Float16* __restrict__ Qp = Qh + ((((size_t)mod * 8 + b) * 8 + h) * 512 + q0 + w * 16) * 64;
    h8 qf0 = *reinterpret_cast<const h8*>(&Qp[(size_t)lr * 64 + lk]);
    h8 qf1 = *reinterpret_cast<const h8*>(&Qp[(size_t)lr * 64 + 32 + lk]);

    const int* __restrict__ mk = (mod == 0) ? m0 : ((mod == 1) ? m1 : m2);
    const bool msk = mk[b * 512 + q0 + w * 16 + lr] != 0;

    float mrow = -3.0e38f, lsum = 0.f;
    f4 o[4] = {};

    const int sr = t >> 3, skk = (t & 7) * 8;       // 512 thr: sr 0..63
    const _Float16* __restrict__ kSrc = Kh + (size_t)bh * 1536 * 64;
    const _Float16* __restrict__ vSrc = Vt + (size_t)bh * 64 * 1536 + (size_t)sr * 1536;

    h8 krg[2], vrg[2];
    krg[0] = *reinterpret_cast<const h8*>(kSrc + (size_t)sr * 64 + skk);
    krg[1] = *reinterpret_cast<const h8*>(kSrc + (size_t)(sr + 64) * 64 + skk);
    vrg[0] = *reinterpret_cast<const h8*>(vSrc + skk);
    vrg[1] = *reinterpret_cast<const h8*>(vSrc + skk + 64);
    *reinterpret_cast<h8*>(&Ks[sr * 72 + skk]) = krg[0];
    *reinterpret_cast<h8*>(&Ks[(sr + 64) * 72 + skk]) = krg[1];
    *reinterpret_cast<h8*>(&Vs[sr * 136 + skk]) = vrg[0];
    *reinterpret_cast<h8*>(&Vs[sr * 136 + skk + 64]) = vrg[1];

    for (int c0 = 0; c0 < 1536; c0 += 128) {
        __syncthreads();                       // staged K/V visible
        const bool more = (c0 + 128) < 1536;
        if (more) {                            // issue next-chunk loads early
            const int cn = c0 + 128;
            krg[0] = *reinterpret_cast<const h8*>(kSrc + (size_t)(cn + sr) * 64 + skk);
            krg[1] = *reinterpret_cast<const h8*>(kSrc + (size_t)(cn + sr + 64) * 64 + skk);
            vrg[0] = *reinterpret_cast<const h8*>(vSrc + cn + skk);
            vrg[1] = *reinterpret_cast<const h8*>(vSrc + cn + skk + 64);
        }

        // S^T = K Q^T : 128 keys
        f4 st[8] = {};
        __builtin_amdgcn_s_setprio(1);
#pragma unroll
        for (int kb = 0; kb < 8; kb++) {
            h8 ka0 = *reinterpret_cast<h8*>(&Ks[(kb * 16 + lr) * 72 + lk]);
            h8 ka1 = *reinterpret_cast<h8*>(&Ks[(kb * 16 + lr) * 72 + 32 + lk]);
            st[kb] = __builtin_amdgcn_mfma_f32_16x16x32_f16(ka0, qf0, st[kb], 0, 0, 0);
            st[kb] = __builtin_amdgcn_mfma_f32_16x16x32_f16(ka1, qf1, st[kb], 0, 0, 0);
        }
        __builtin_amdgcn_s_setprio(0);

        if (!msk) {
#pragma unroll
            for (int kb = 0; kb < 8; kb++) { st[kb][0] = NEGV; st[kb][1] = NEGV; st[kb][2] = NEGV; st[kb][3] = NEGV; }
        }
        float cm = -3.0e38f;
#pragma unroll
        for (int kb = 0; kb < 8; kb++)
            cm = fmaxf(cm, fmaxf(fmaxf(st[kb][0], st[kb][1]), fmaxf(st[kb][2], st[kb][3])));
        cm = fmaxf(cm, __shfl_xor(cm, 16));
        cm = fmaxf(cm, __shfl_xor(cm, 32));

        if (!__all(cm <= mrow + 8.0f)) {       // defer-max
            const float mn = fmaxf(mrow, cm);
            const float sc = __builtin_amdgcn_exp2f(mrow - mn);
            mrow = mn;
            lsum *= sc;
#pragma unroll
            for (int dg = 0; dg < 4; dg++) o[dg] *= sc;
        }

        float rs = 0.f;
#pragma unroll
        for (int kb = 0; kb < 8; kb++) {
            const float p0 = __builtin_amdgcn_exp2f(st[kb][0] - mrow);
            const float p1 = __builtin_amdgcn_exp2f(st[kb][1] - mrow);
            const float p2 = __builtin_amdgcn_exp2f(st[kb][2] - mrow);
            const float p3 = __builtin_amdgcn_exp2f(st[kb][3] - mrow);
            rs += (p0 + p1) + (p2 + p3);
            h4 ph = { (_Float16)p0, (_Float16)p1, (_Float16)p2, (_Float16)p3 };
            *reinterpret_cast<h4*>(&Ps[(w * 16 + lr) * 136 + kb * 16 + lg * 4]) = ph;
        }
        rs += __shfl_xor(rs, 16);
        rs += __shfl_xor(rs, 32);
        lsum += rs;

        // O^T += V^T P (Ps rows wave-local: in-wave DS order suffices)
        __builtin_amdgcn_s_setprio(1);
#pragma unroll
        for (int kb2 = 0; kb2 < 4; kb2++) {
            h8 pa = *reinterpret_cast<h8*>(&Ps[(w * 16 + lr) * 136 + kb2 * 32 + lk]);
#pragma unroll
            for (int dg = 0; dg < 4; dg++) {
                h8 va = *reinterpret_cast<h8*>(&Vs[(dg * 16 + lr) * 136 + kb2 * 32 + lk]);
                o[dg] = __builtin_amdgcn_mfma_f32_16x16x32_f16(va, pa, o[dg], 0, 0, 0);
            }
        }
        __builtin_amdgcn_s_setprio(0);

        __syncthreads();                       // all K/V reads done
        if (more) {                            // write-late
            *reinterpret_cast<h8*>(&Ks[sr * 72 + skk]) = krg[0];
            *reinterpret_cast<h8*>(&Ks[(sr + 64) * 72 + skk]) = krg[1];
            *reinterpret_cast<h8*>(&Vs[sr * 136 + skk]) = vrg[0];
            *reinterpret_cast<h8*>(&Vs[sr * 136 + skk + 64]) = vrg[1];
        }
    }

    const float inv = 1.f / lsum;
    const size_t row = (size_t)mod * 4096 + b * 512 + q0 + w * 16 + lr;
#pragma unroll
    for (int dg = 0; dg < 4; dg++) {
        h4 ov = { (_Float16)(o[dg][0] * inv), (_Float16)(o[dg][1] * inv),
                  (_Float16)(o[dg][2] * inv), (_Float16)(o[dg][3] * inv) };
        *reinterpret_cast<h4*>(&Oh[row * 512 + h * 64 + dg * 16 + lg * 4]) = ov;
    }
}

// ======================= output projection: barrier-free reg-resident =======================
// 1 wave per block. Wave owns 16 rows x 128 cols; K=512 streamed. A from Oh (L2),
// B = Wot^T frags double-buffered in regs. Zero LDS, zero barriers.
// grid (4 colchunks, 256 rowgrps, 3 mods) = 3072 waves = 12/CU.
__global__ __launch_bounds__(64) void out_gemm_f16(
    const _Float16* __restrict__ Oh, const _Float16* __restrict__ Wot,
    float* __restrict__ out)
{
    const int mod = blockIdx.z, rg = blockIdx.y, cc = blockIdx.x;
    const _Float16* __restrict__ Ap = Oh  + ((size_t)mod * 4096 + rg * 16) * 512;
    const _Float16* __restrict__ Bp = Wot + (size_t)mod * 512 * 512 + (size_t)cc * 128 * 512;
    float* __restrict__ C = out + ((size_t)mod * 4096 + rg * 16) * 512 + cc * 128;

    const int l = threadIdx.x, lr = l & 15, lg = l >> 4;

    f4 acc[8] = {};
    h8 bcur[8], bnxt[8];
#pragma unroll
    for (int cb = 0; cb < 8; cb++)
        bcur[cb] = *reinterpret_cast<const h8*>(&Bp[(size_t)(cb * 16 + lr) * 512 + lg * 8]);

#pragma unroll
    for (int ks = 0; ks < 16; ks++) {
        const h8 a = *reinterpret_cast<const h8*>(&Ap[(size_t)lr * 512 + ks * 32 + lg * 8]);
        if (ks < 15) {
#pragma unroll
            for (int cb = 0; cb < 8; cb++)
                bnxt[cb] = *reinterpret_cast<const h8*>(&Bp[(size_t)(cb * 16 + lr) * 512 + (ks + 1) * 32 + lg * 8]);
        }
        __builtin_amdgcn_s_setprio(1);
#pragma unroll
        for (int cb = 0; cb < 8; cb++)
            acc[cb] = __builtin_amdgcn_mfma_f32_16x16x32_f16(a, bcur[cb], acc[cb], 0, 0, 0);
        __builtin_amdgcn_s_setprio(0);
#pragma unroll
        for (int cb = 0; cb < 8; cb++) bcur[cb] = bnxt[cb];
    }

    // C layout: row = lg*4+reg, col = cb*16+lr; 16 lanes -> 64B contiguous
#pragma unroll
    for (int cb = 0; cb < 8; cb++)
#pragma unroll
        for (int reg = 0; reg < 4; reg++)
            C[(size_t)(lg * 4 + reg) * 512 + cb * 16 + lr] = acc[cb][reg];
}

extern "C" void kernel_launch(void* const* d_in, const int* in_sizes, int n_in,
                              void* d_out, int out_size, void* d_ws, size_t ws_size,
                              hipStream_t stream)
{
    // interleaved inputs: x0,m0,Wqkv0,Wout0, x1,m1,Wqkv1,Wout1, x2,m2,Wqkv2,Wout2
    const float* x0  = (const float*)d_in[0];
    const int*   m0  = (const int*)  d_in[1];
    const float* Wq0 = (const float*)d_in[2];
    const float* Wo0 = (const float*)d_in[3];
    const float* x1  = (const float*)d_in[4];
    const int*   m1  = (const int*)  d_in[5];
    const float* Wq1 = (const float*)d_in[6];
    const float* Wo1 = (const float*)d_in[7];
    const float* x2  = (const float*)d_in[8];
    const int*   m2  = (const int*)  d_in[9];
    const float* Wq2 = (const float*)d_in[10];
    const float* Wo2 = (const float*)d_in[11];

    _Float16* Wqt = (_Float16*)d_ws;       // 2359296
    _Float16* Wot = Wqt + 2359296;         //  786432
    _Float16* Qh  = Wot + 786432;          // 6291456
    _Float16* Kh  = Qh  + 6291456;         // 6291456
    _Float16* Vt  = Kh  + 6291456;         // 6291456
    _Float16* Oh  = Vt  + 6291456;         // 6291456

    wt_cvt<<<dim3(1024, 1, 3), 256, 0, stream>>>(Wq0, Wq1, Wq2, Wo0, Wo1, Wo2, Wqt, Wot);
    qkv_gemm_f16<<<dim3(32, 12, 3), 256, 0, stream>>>(x0, x1, x2, Wqt, Qh, Kh, Vt);
    attn_f16    <<<dim3(64, 4, 3), 512, 0, stream>>>(Qh, Kh, Vt, m0, m1, m2, Oh);
    out_gemm_f16<<<dim3(4, 256, 3), 64, 0, stream>>>(Oh, Wot, (float*)d_out);
}